// Round 1
// baseline (384.838 us; speedup 1.0000x reference)
//
#include <hip/hip_runtime.h>
#include <math.h>

// Problem shapes (fixed by reference setup_inputs):
//   encoded [B=4, C=256, H=256, W=256] fp32, masks [B,1,H,W] int32 in [0,32]
//   w1 [256,128], b1 [128], w2 [128,4], b2 [4]  -> out [B,32,4] fp32
#define BATCH   4
#define CH      256
#define PIX     65536   // 256*256
#define NIDS    33      // ids 0..32 (0 = background, dropped)
#define NOBJ    32

// ---------------------------------------------------------------------------
// Kernel 1: per-(b,c) segmented max over 65536 pixels.
// Grid: B*CH = 1024 blocks, 256 threads.
// Each thread keeps a private 33-entry max column in LDS at smax[id*256 + t]:
// every lane always hits bank (t % 32) -> fixed 2-way aliasing (free on gfx950).
// ---------------------------------------------------------------------------
__global__ __launch_bounds__(256, 1) void segmax_kernel(
    const float* __restrict__ encoded,
    const int*   __restrict__ masks,
    float*       __restrict__ pooled)   // [B, NOBJ, CH]
{
    __shared__ float smax[NIDS * 256];
    __shared__ float partial[NOBJ * 8];

    const int t   = threadIdx.x;
    const int bid = blockIdx.x;       // = b*256 + c
    const int b   = bid >> 8;
    const int c   = bid & 255;

    #pragma unroll
    for (int i = 0; i < NIDS; ++i)
        smax[i * 256 + t] = -INFINITY;
    __syncthreads();

    const float4* __restrict__ vals = (const float4*)(encoded + (size_t)bid * PIX);
    const int4*   __restrict__ ids  = (const int4*)(masks + (size_t)b * PIX);

    // 65536 / (256 threads * 4) = 64 iterations
    #pragma unroll 2
    for (int it = 0; it < 64; ++it) {
        const int idx = it * 256 + t;
        const float4 v = vals[idx];
        const int4   m = ids[idx];
        { float* p = &smax[m.x * 256 + t]; *p = fmaxf(*p, v.x); }
        { float* p = &smax[m.y * 256 + t]; *p = fmaxf(*p, v.y); }
        { float* p = &smax[m.z * 256 + t]; *p = fmaxf(*p, v.z); }
        { float* p = &smax[m.w * 256 + t]; *p = fmaxf(*p, v.w); }
    }
    __syncthreads();

    // Stage 1: 256 threads = 32 ids x 8 groups of 32 entries each.
    // Per-lane rotation (j+t)&31 keeps the 64 lanes spread over banks.
    {
        const int id   = 1 + (t >> 3);   // ids 1..32 (skip background 0)
        const int g    = t & 7;
        const int base = id * 256 + g * 32;
        float m = -INFINITY;
        #pragma unroll
        for (int j = 0; j < 32; ++j) {
            const int jj = (j + t) & 31;
            m = fmaxf(m, smax[base + jj]);
        }
        partial[(id - 1) * 8 + g] = m;
    }
    __syncthreads();

    if (t < NOBJ) {
        float m = -INFINITY;
        #pragma unroll
        for (int g = 0; g < 8; ++g) m = fmaxf(m, partial[t * 8 + g]);
        m = fmaxf(m, 0.0f);             // maximum(seg, 0): clamps + fills empty segs
        pooled[((size_t)b * NOBJ + t) * CH + c] = m;
    }
}

// ---------------------------------------------------------------------------
// Kernel 2: tiny MLP. One block per pooled row (B*NOBJ = 128 rows).
//   h = row @ w1 + b1  (256 -> 128, no activation)
//   out = sigmoid(h @ w2 + b2)  (128 -> 4)
// ---------------------------------------------------------------------------
__global__ __launch_bounds__(128, 1) void mlp_kernel(
    const float* __restrict__ pooled,
    const float* __restrict__ w1, const float* __restrict__ b1,
    const float* __restrict__ w2, const float* __restrict__ b2,
    float*       __restrict__ out)
{
    __shared__ float row[CH];
    __shared__ float h[128];
    const int t = threadIdx.x;
    const int r = blockIdx.x;          // 0..127 = b*32 + n

    row[t]       = pooled[(size_t)r * CH + t];
    row[t + 128] = pooled[(size_t)r * CH + t + 128];
    __syncthreads();

    float acc = b1[t];
    #pragma unroll 8
    for (int i = 0; i < CH; ++i)
        acc = fmaf(row[i], w1[i * 128 + t], acc);   // w1 coalesced over t
    h[t] = acc;
    __syncthreads();

    if (t < 4) {
        float a = b2[t];
        #pragma unroll 8
        for (int i = 0; i < 128; ++i)
            a = fmaf(h[i], w2[i * 4 + t], a);
        out[(size_t)r * 4 + t] = 1.0f / (1.0f + expf(-a));
    }
}

extern "C" void kernel_launch(void* const* d_in, const int* in_sizes, int n_in,
                              void* d_out, int out_size, void* d_ws, size_t ws_size,
                              hipStream_t stream) {
    // setup_inputs() dict order: encoded, w1, b1, w2, b2, masks
    const float* encoded = (const float*)d_in[0];
    const float* w1      = (const float*)d_in[1];
    const float* b1      = (const float*)d_in[2];
    const float* w2      = (const float*)d_in[3];
    const float* b2      = (const float*)d_in[4];
    const int*   masks   = (const int*)  d_in[5];
    float* out    = (float*)d_out;
    float* pooled = (float*)d_ws;      // [B, NOBJ, CH] = 32768 floats = 128 KiB

    segmax_kernel<<<BATCH * CH, 256, 0, stream>>>(encoded, masks, pooled);
    mlp_kernel<<<BATCH * NOBJ, 128, 0, stream>>>(pooled, w1, b1, w2, b2, out);
}

// Round 2
// 356.819 us; speedup vs baseline: 1.0785x; 1.0785x over previous
//
#include <hip/hip_runtime.h>
#include <math.h>

// Shapes: encoded [B=4, C=256, 256, 256] fp32, masks [B,1,256,256] int32 in [0,32]
// w1 [256,128], b1 [128], w2 [128,4], b2 [4] -> out [B,32,4] fp32
#define BATCH   4
#define CH      256
#define PIX     65536
#define NIDS    33
#define NOBJ    32
#define SSPLIT  2
#define F4_SLICE (PIX / 4)              // float4s per (b,c) slice = 16384
#define F4_PER_S (F4_SLICE / SSPLIT)    // 8192
#define ITERS    (F4_PER_S / 256)       // 32

typedef float f32x4 __attribute__((ext_vector_type(4)));

// ---------------------------------------------------------------------------
// Kernel 0: pack int32 ids (0..32) into uint8. Shrinks the mask resident set
// from 4 MB (one whole XCD L2) to 256 KB -> stays L2-hot on every XCD, and
// cuts logical mask traffic 4x (1 GB -> 256 MB, all L2-served).
// ---------------------------------------------------------------------------
__global__ __launch_bounds__(256) void pack_masks_kernel(
    const int* __restrict__ masks, unsigned int* __restrict__ maskw)
{
    const int idx = blockIdx.x * 256 + threadIdx.x;   // 65536 threads x 4 ids
    const int4 v = ((const int4*)masks)[idx];
    maskw[idx] = (unsigned)v.x | ((unsigned)v.y << 8) |
                 ((unsigned)v.z << 16) | ((unsigned)v.w << 24);
}

// ---------------------------------------------------------------------------
// Kernel 1: segmented max. Grid = B*CH*SSPLIT = 2048 blocks, 256 threads.
// Block (slice, s) processes pixels [s*32768, (s+1)*32768) of one (b,c) slice.
// Per-thread private 33-entry max column in LDS: smax[id*256 + t] -> every
// lane hits bank t%32 -> fixed 2-way aliasing (free). encoded loads are
// non-temporal (pure stream, keep L2 for masks).
// ---------------------------------------------------------------------------
__global__ __launch_bounds__(256, 1) void segmax_kernel(
    const float*        __restrict__ encoded,
    const unsigned int* __restrict__ maskw,
    float*              __restrict__ pooledP)   // [SSPLIT, B, NOBJ, CH]
{
    __shared__ float smax[NIDS * 256];
    __shared__ float partial[NOBJ * 8];

    const int t     = threadIdx.x;
    const int slice = blockIdx.x >> 1;    // b*256 + c
    const int s     = blockIdx.x & 1;
    const int b     = slice >> 8;
    const int c     = slice & 255;

    #pragma unroll
    for (int i = 0; i < NIDS; ++i)
        smax[i * 256 + t] = -INFINITY;
    __syncthreads();

    const f32x4* __restrict__ vals =
        (const f32x4*)encoded + (size_t)slice * F4_SLICE + (size_t)s * F4_PER_S;
    const unsigned int* __restrict__ mw =
        maskw + (size_t)b * F4_SLICE + (size_t)s * F4_PER_S;

    // explicit 1-ahead prefetch: loads issue before the LDS RMW wait chain
    f32x4 v = __builtin_nontemporal_load(vals + t);
    unsigned int m = mw[t];

    #pragma unroll 4
    for (int it = 0; it < ITERS; ++it) {
        f32x4 nv;
        unsigned int nm = 0;
        if (it + 1 < ITERS) {
            nv = __builtin_nontemporal_load(vals + (it + 1) * 256 + t);
            nm = mw[(it + 1) * 256 + t];
        }
        { float* p = &smax[((m      ) & 255) * 256 + t]; *p = fmaxf(*p, v.x); }
        { float* p = &smax[((m >>  8) & 255) * 256 + t]; *p = fmaxf(*p, v.y); }
        { float* p = &smax[((m >> 16) & 255) * 256 + t]; *p = fmaxf(*p, v.z); }
        { float* p = &smax[((m >> 24)      ) * 256 + t]; *p = fmaxf(*p, v.w); }
        v = nv; m = nm;
    }
    __syncthreads();

    // Stage 1: 256 threads = 32 ids x 8 groups of 32 entries; per-lane
    // rotation (j+t)&31 keeps the 64 lanes spread over banks.
    {
        const int id   = 1 + (t >> 3);    // ids 1..32 (drop background 0)
        const int g    = t & 7;
        const int base = id * 256 + g * 32;
        float mx = -INFINITY;
        #pragma unroll
        for (int j = 0; j < 32; ++j) {
            const int jj = (j + t) & 31;
            mx = fmaxf(mx, smax[base + jj]);
        }
        partial[(id - 1) * 8 + g] = mx;
    }
    __syncthreads();

    if (t < NOBJ) {
        float mx = -INFINITY;
        #pragma unroll
        for (int g = 0; g < 8; ++g) mx = fmaxf(mx, partial[t * 8 + g]);
        // no clamp here: clamp after merging the SSPLIT partials in kernel 2
        pooledP[((size_t)s * BATCH * NOBJ + (size_t)b * NOBJ + t) * CH + c] = mx;
    }
}

// ---------------------------------------------------------------------------
// Kernel 2: merge SSPLIT partials, clamp at 0, then tiny MLP + sigmoid.
// One block (256 thr) per pooled row; split-K by 2 for layer 1.
// ---------------------------------------------------------------------------
__global__ __launch_bounds__(256, 1) void mlp_kernel(
    const float* __restrict__ pooledP,
    const float* __restrict__ w1, const float* __restrict__ b1,
    const float* __restrict__ w2, const float* __restrict__ b2,
    float*       __restrict__ out)
{
    __shared__ float row[CH];
    __shared__ float hpart[256];
    __shared__ float h[128];
    const int t = threadIdx.x;
    const int r = blockIdx.x;          // 0..127 = b*32 + n

    {
        const float p0 = pooledP[(size_t)r * CH + t];
        const float p1 = pooledP[((size_t)BATCH * NOBJ + r) * CH + t];
        row[t] = fmaxf(fmaxf(p0, p1), 0.0f);   // maximum(seg, 0) incl. empty segs
    }
    __syncthreads();

    {
        const int j  = t & 127;
        const int kh = t >> 7;         // K-half 0/1
        float acc = (kh == 0) ? b1[j] : 0.0f;
        const int kbase = kh * 128;
        #pragma unroll 8
        for (int i = 0; i < 128; ++i)
            acc = fmaf(row[kbase + i], w1[(kbase + i) * 128 + j], acc);
        hpart[t] = acc;
    }
    __syncthreads();
    if (t < 128) h[t] = hpart[t] + hpart[t + 128];
    __syncthreads();

    if (t < 4) {
        float a = b2[t];
        #pragma unroll 8
        for (int i = 0; i < 128; ++i)
            a = fmaf(h[i], w2[i * 4 + t], a);
        out[(size_t)r * 4 + t] = 1.0f / (1.0f + expf(-a));
    }
}

extern "C" void kernel_launch(void* const* d_in, const int* in_sizes, int n_in,
                              void* d_out, int out_size, void* d_ws, size_t ws_size,
                              hipStream_t stream) {
    // setup_inputs() dict order: encoded, w1, b1, w2, b2, masks
    const float* encoded = (const float*)d_in[0];
    const float* w1      = (const float*)d_in[1];
    const float* b1      = (const float*)d_in[2];
    const float* w2      = (const float*)d_in[3];
    const float* b2      = (const float*)d_in[4];
    const int*   masks   = (const int*)  d_in[5];
    float* out = (float*)d_out;

    // workspace layout: [0, 256KB) packed masks, [256KB, 512KB) pooled partials
    unsigned int* maskw  = (unsigned int*)d_ws;             // B*PIX/4 words
    float*        pooledP = (float*)d_ws + BATCH * F4_SLICE; // [2, B, NOBJ, CH]

    pack_masks_kernel<<<BATCH * PIX / 4 / 256, 256, 0, stream>>>(masks, maskw);
    segmax_kernel<<<BATCH * CH * SSPLIT, 256, 0, stream>>>(encoded, maskw, pooledP);
    mlp_kernel<<<BATCH * NOBJ, 256, 0, stream>>>(pooledP, w1, b1, w2, b2, out);
}